// Round 1
// baseline (862.959 us; speedup 1.0000x reference)
//
#include <hip/hip_runtime.h>
#include <math.h>

#define NN 100000
#define NE 1600000
#define DH 128
#define DO2 64
#define BN_EPS 1e-5f
#define NB1 ((NN + 1023) / 1024)

// ---------------- CSR build ----------------
__global__ __launch_bounds__(256) void hist_k(const int* __restrict__ dst, int* __restrict__ deg) {
    int e = blockIdx.x * 256 + threadIdx.x;
    if (e < NE) atomicAdd(&deg[dst[e]], 1);
}

__global__ __launch_bounds__(1024) void scan1_k(const int* __restrict__ deg, int* __restrict__ rp,
                                                int* __restrict__ bsum) {
    __shared__ int s[1024];
    int tid = threadIdx.x;
    int i = blockIdx.x * 1024 + tid;
    int v = (i < NN) ? deg[i] : 0;
    s[tid] = v;
    __syncthreads();
    for (int off = 1; off < 1024; off <<= 1) {
        int t = (tid >= off) ? s[tid - off] : 0;
        __syncthreads();
        s[tid] += t;
        __syncthreads();
    }
    if (i < NN) rp[i] = s[tid] - v;            // exclusive within block
    if (tid == 1023) bsum[blockIdx.x] = s[1023];
}

__global__ __launch_bounds__(128) void scan2_k(int* __restrict__ bsum) {
    __shared__ int s[128];
    int tid = threadIdx.x;
    int v = (tid < NB1) ? bsum[tid] : 0;
    s[tid] = v;
    __syncthreads();
    for (int off = 1; off < 128; off <<= 1) {
        int t = (tid >= off) ? s[tid - off] : 0;
        __syncthreads();
        s[tid] += t;
        __syncthreads();
    }
    if (tid < NB1) bsum[tid] = s[tid] - v;     // exclusive
}

__global__ __launch_bounds__(256) void scan3_k(int* __restrict__ rp, const int* __restrict__ bsum,
                                               int* __restrict__ cur) {
    int i = blockIdx.x * 256 + threadIdx.x;
    if (i < NN) {
        int val = rp[i] + bsum[i >> 10];
        rp[i] = val;
        cur[i] = val;                          // cursor for fill
    }
    if (i == 0) rp[NN] = NE;
}

__global__ __launch_bounds__(256) void fill_k(const int* __restrict__ ei, int* __restrict__ cur,
                                              int* __restrict__ col) {
    int e = blockIdx.x * 256 + threadIdx.x;
    if (e < NE) {
        int s = ei[e];          // src
        int d = ei[NE + e];     // dst
        int pos = atomicAdd(&cur[d], 1);
        col[pos] = s;
    }
}

// ---------------- aggregation: agg[i] = x[i] + sum_{j->i} x[j] ----------------
// 8 nodes/block, 32 threads/node, float4 per thread (128 dims).
__global__ __launch_bounds__(256) void agg_k(const float* __restrict__ x, const int* __restrict__ rp,
                                             const int* __restrict__ col, float* __restrict__ agg) {
    int node = blockIdx.x * 8 + (threadIdx.x >> 5);
    int ch = threadIdx.x & 31;
    const float4* xv = (const float4*)x;
    float4 a = xv[node * 32 + ch];
    int beg = rp[node], end = rp[node + 1];
    for (int p = beg; p < end; ++p) {
        int s = col[p];
        float4 v = xv[s * 32 + ch];
        a.x += v.x; a.y += v.y; a.z += v.z; a.w += v.w;
    }
    ((float4*)agg)[node * 32 + ch] = a;
}

// ---------------- fp32 tiled GEMM, out = epi(A @ W + b) ----------------
// TM=64 rows/block, KT=32 k-chunk. EPI: 0 = relu, 1 = BN+relu+residual, 2 = log_softmax.
// In-place-safe over A (block writes only rows it fully read, after the k-loop).
template <int DOUT, int EPI>
__global__ __launch_bounds__(256, 2) void gemm_k(
    const float* __restrict__ A, const float* __restrict__ W, const float* __restrict__ bias,
    const float* __restrict__ bng, const float* __restrict__ bnb,
    const float* __restrict__ bnm, const float* __restrict__ bnv,
    const float* __restrict__ xres, float* __restrict__ out) {
    constexpr int TM = 64;
    constexpr int KT = 32;
    constexpr int NCG = DOUT / 4;   // col groups (32 or 16)
    constexpr int NRG = 256 / NCG;  // row groups (8 or 16)
    constexpr int RPT = TM / NRG;   // rows per thread (8 or 4)

    const int t = threadIdx.x;
    const int cg = t % NCG;
    const int rg = t / NCG;
    const int r0 = blockIdx.x * TM;

    __shared__ float Ws[KT * DOUT];      // k-chunk of W
    __shared__ float xs[KT][TM + 4];     // transposed x tile, pad stride 68

    float acc[RPT][4];
#pragma unroll
    for (int i = 0; i < RPT; ++i)
#pragma unroll
        for (int j = 0; j < 4; ++j) acc[i][j] = 0.f;

    for (int kt = 0; kt < DH; kt += KT) {
        __syncthreads();
        // stage W chunk: KT*DOUT floats
        for (int i = t * 4; i < KT * DOUT; i += 1024)
            *(float4*)&Ws[i] = *(const float4*)&W[kt * DOUT + i];
        // stage x tile transposed: 64 rows x 32 k
        {
            int row = t >> 2;
            int kq = t & 3;
            bool ok = (r0 + row) < NN;
            const float* src = A + (size_t)(r0 + row) * DH + kt + kq * 8;
            float4 v0 = ok ? *(const float4*)src : make_float4(0.f, 0.f, 0.f, 0.f);
            float4 v1 = ok ? *(const float4*)(src + 4) : make_float4(0.f, 0.f, 0.f, 0.f);
            int kb = kq * 8;
            xs[kb + 0][row] = v0.x; xs[kb + 1][row] = v0.y;
            xs[kb + 2][row] = v0.z; xs[kb + 3][row] = v0.w;
            xs[kb + 4][row] = v1.x; xs[kb + 5][row] = v1.y;
            xs[kb + 6][row] = v1.z; xs[kb + 7][row] = v1.w;
        }
        __syncthreads();
#pragma unroll
        for (int k = 0; k < KT; ++k) {
            float4 wv = *(const float4*)&Ws[k * DOUT + cg * 4];
            const float4* xp = (const float4*)&xs[k][rg * RPT];
#pragma unroll
            for (int i4 = 0; i4 < RPT / 4; ++i4) {
                float4 xq = xp[i4];
                float xv[4] = {xq.x, xq.y, xq.z, xq.w};
#pragma unroll
                for (int ii = 0; ii < 4; ++ii) {
                    int i = i4 * 4 + ii;
                    acc[i][0] += xv[ii] * wv.x;
                    acc[i][1] += xv[ii] * wv.y;
                    acc[i][2] += xv[ii] * wv.z;
                    acc[i][3] += xv[ii] * wv.w;
                }
            }
        }
    }

    const int c0 = cg * 4;
    if constexpr (EPI == 0) {  // relu
        float4 bv = *(const float4*)&bias[c0];
#pragma unroll
        for (int i = 0; i < RPT; ++i) {
            int row = r0 + rg * RPT + i;
            if (row < NN) {
                float4 o;
                o.x = fmaxf(acc[i][0] + bv.x, 0.f);
                o.y = fmaxf(acc[i][1] + bv.y, 0.f);
                o.z = fmaxf(acc[i][2] + bv.z, 0.f);
                o.w = fmaxf(acc[i][3] + bv.w, 0.f);
                *(float4*)&out[(size_t)row * DOUT + c0] = o;
            }
        }
    } else if constexpr (EPI == 1) {  // BN + relu + residual
        float4 bv = *(const float4*)&bias[c0];
        float4 g4 = *(const float4*)&bng[c0];
        float4 b4 = *(const float4*)&bnb[c0];
        float4 m4 = *(const float4*)&bnm[c0];
        float4 v4 = *(const float4*)&bnv[c0];
        float sc[4], off[4];
        sc[0] = g4.x * rsqrtf(v4.x + BN_EPS); off[0] = (bv.x - m4.x) * sc[0] + b4.x;
        sc[1] = g4.y * rsqrtf(v4.y + BN_EPS); off[1] = (bv.y - m4.y) * sc[1] + b4.y;
        sc[2] = g4.z * rsqrtf(v4.z + BN_EPS); off[2] = (bv.z - m4.z) * sc[2] + b4.z;
        sc[3] = g4.w * rsqrtf(v4.w + BN_EPS); off[3] = (bv.w - m4.w) * sc[3] + b4.w;
#pragma unroll
        for (int i = 0; i < RPT; ++i) {
            int row = r0 + rg * RPT + i;
            if (row < NN) {
                float4 xr = *(const float4*)&xres[(size_t)row * DH + c0];
                float4 o;
                o.x = fmaxf(acc[i][0] * sc[0] + off[0], 0.f) + xr.x;
                o.y = fmaxf(acc[i][1] * sc[1] + off[1], 0.f) + xr.y;
                o.z = fmaxf(acc[i][2] * sc[2] + off[2], 0.f) + xr.z;
                o.w = fmaxf(acc[i][3] * sc[3] + off[3], 0.f) + xr.w;
                *(float4*)&out[(size_t)row * DH + c0] = o;
            }
        }
    } else {  // EPI == 2: log_softmax over DOUT=64 (row spans 16 consecutive lanes)
        float4 bv = *(const float4*)&bias[c0];
#pragma unroll
        for (int i = 0; i < RPT; ++i) {
            float v0 = acc[i][0] + bv.x, v1 = acc[i][1] + bv.y;
            float v2 = acc[i][2] + bv.z, v3 = acc[i][3] + bv.w;
            float mx = fmaxf(fmaxf(v0, v1), fmaxf(v2, v3));
            for (int d = 1; d < 16; d <<= 1) mx = fmaxf(mx, __shfl_xor(mx, d));
            float sm = expf(v0 - mx) + expf(v1 - mx) + expf(v2 - mx) + expf(v3 - mx);
            for (int d = 1; d < 16; d <<= 1) sm += __shfl_xor(sm, d);
            float L = mx + logf(sm);
            int row = r0 + rg * RPT + i;
            if (row < NN) {
                float4 o = make_float4(v0 - L, v1 - L, v2 - L, v3 - L);
                *(float4*)&out[(size_t)row * DO2 + c0] = o;
            }
        }
    }
}

extern "C" void kernel_launch(void* const* d_in, const int* in_sizes, int n_in,
                              void* d_out, int out_size, void* d_ws, size_t ws_size,
                              hipStream_t stream) {
    const float* x = (const float*)d_in[0];
    const int* ei = (const int*)d_in[1];
    const float* W1_0 = (const float*)d_in[2];
    const float* b1_0 = (const float*)d_in[3];
    const float* W2_0 = (const float*)d_in[4];
    const float* b2_0 = (const float*)d_in[5];
    const float* W1_1 = (const float*)d_in[6];
    const float* b1_1 = (const float*)d_in[7];
    const float* W2_1 = (const float*)d_in[8];
    const float* b2_1 = (const float*)d_in[9];
    const float* W1_2 = (const float*)d_in[10];
    const float* b1_2 = (const float*)d_in[11];
    const float* W2_2 = (const float*)d_in[12];
    const float* b2_2 = (const float*)d_in[13];
    const float* g0 = (const float*)d_in[14];
    const float* be0 = (const float*)d_in[15];
    const float* m0 = (const float*)d_in[16];
    const float* v0 = (const float*)d_in[17];
    const float* g1 = (const float*)d_in[18];
    const float* be1 = (const float*)d_in[19];
    const float* m1 = (const float*)d_in[20];
    const float* v1 = (const float*)d_in[21];
    float* out = (float*)d_out;

    // workspace layout (bytes): x_cur 51.2M | aggh 51.2M | rp 400128 | cur 400128 | col 6.4M | bsum 512
    char* ws = (char*)d_ws;
    float* x_cur = (float*)(ws);
    float* aggh = (float*)(ws + 51200000);
    int* rp = (int*)(ws + 102400000);
    int* cur = (int*)(ws + 102400000 + 400128);
    int* col = (int*)(ws + 102400000 + 800256);
    int* bsum = (int*)(ws + 102400000 + 800256 + 6400000);

    // --- CSR build (deterministic structure; intra-row order varies at ulp level only) ---
    hipMemsetAsync(cur, 0, NN * sizeof(int), stream);
    hist_k<<<(NE + 255) / 256, 256, 0, stream>>>(ei + NE, cur);
    scan1_k<<<NB1, 1024, 0, stream>>>(cur, rp, bsum);
    scan2_k<<<1, 128, 0, stream>>>(bsum);
    scan3_k<<<(NN + 255) / 256, 256, 0, stream>>>(rp, bsum, cur);
    fill_k<<<(NE + 255) / 256, 256, 0, stream>>>(ei, cur, col);

    const int GA = NN / 8;         // 12500
    const int GG = (NN + 63) / 64; // 1563

    // layer 0
    agg_k<<<GA, 256, 0, stream>>>(x, rp, col, aggh);
    gemm_k<128, 0><<<GG, 256, 0, stream>>>(aggh, W1_0, b1_0, nullptr, nullptr, nullptr, nullptr, nullptr, aggh);
    gemm_k<128, 1><<<GG, 256, 0, stream>>>(aggh, W2_0, b2_0, g0, be0, m0, v0, x, x_cur);
    // layer 1
    agg_k<<<GA, 256, 0, stream>>>(x_cur, rp, col, aggh);
    gemm_k<128, 0><<<GG, 256, 0, stream>>>(aggh, W1_1, b1_1, nullptr, nullptr, nullptr, nullptr, nullptr, aggh);
    gemm_k<128, 1><<<GG, 256, 0, stream>>>(aggh, W2_1, b2_1, g1, be1, m1, v1, x_cur, x_cur);
    // layer 2
    agg_k<<<GA, 256, 0, stream>>>(x_cur, rp, col, aggh);
    gemm_k<128, 0><<<GG, 256, 0, stream>>>(aggh, W1_2, b1_2, nullptr, nullptr, nullptr, nullptr, nullptr, aggh);
    gemm_k<64, 2><<<GG, 256, 0, stream>>>(aggh, W2_2, b2_2, nullptr, nullptr, nullptr, nullptr, nullptr, out);
}

// Round 2
// 723.930 us; speedup vs baseline: 1.1920x; 1.1920x over previous
//
#include <hip/hip_runtime.h>
#include <math.h>

#define NN 100000
#define NE 1600000
#define DH 128
#define DO2 64
#define BN_EPS 1e-5f
#define NB 782            // buckets of 128 nodes: ceil(100000/128)
#define EPB 4096          // edges per block in hist/scatter
#define NEB ((NE + EPB - 1) / EPB)   // 391

// ---------------- CSR build via dst-buckets ----------------
__global__ __launch_bounds__(256) void bhist_k(const int* __restrict__ dst, int* __restrict__ bcnt) {
    __shared__ int h[NB];
    for (int i = threadIdx.x; i < NB; i += 256) h[i] = 0;
    __syncthreads();
    int base = blockIdx.x * EPB;
    for (int i = threadIdx.x; i < EPB; i += 256) {
        int e = base + i;
        if (e < NE) atomicAdd(&h[dst[e] >> 7], 1);
    }
    __syncthreads();
    for (int i = threadIdx.x; i < NB; i += 256) {
        int c = h[i];
        if (c) atomicAdd(&bcnt[i], c);
    }
}

__global__ __launch_bounds__(1024) void bscan_k(const int* __restrict__ bcnt, int* __restrict__ bstart,
                                                int* __restrict__ bcur) {
    __shared__ int s[1024];
    int t = threadIdx.x;
    int v = (t < NB) ? bcnt[t] : 0;
    s[t] = v;
    __syncthreads();
    for (int off = 1; off < 1024; off <<= 1) {
        int u = (t >= off) ? s[t - off] : 0;
        __syncthreads();
        s[t] += u;
        __syncthreads();
    }
    int ex = s[t] - v;          // exclusive
    if (t <= NB) bstart[t] = ex;   // t==NB -> NE
    if (t < NB) bcur[t] = ex;
}

__global__ __launch_bounds__(256) void bscat_k(const int* __restrict__ ei, int* __restrict__ bcur,
                                               unsigned* __restrict__ packed) {
    __shared__ int h[NB];
    for (int i = threadIdx.x; i < NB; i += 256) h[i] = 0;
    __syncthreads();
    int base = blockIdx.x * EPB;
    for (int i = threadIdx.x; i < EPB; i += 256) {
        int e = base + i;
        if (e < NE) atomicAdd(&h[ei[NE + e] >> 7], 1);
    }
    __syncthreads();
    for (int i = threadIdx.x; i < NB; i += 256) {
        int c = h[i];
        if (c) h[i] = atomicAdd(&bcur[i], c);   // reserve contiguous range, h[i] = base cursor
    }
    __syncthreads();
    for (int i = threadIdx.x; i < EPB; i += 256) {
        int e = base + i;
        if (e < NE) {
            int d = ei[NE + e];
            int b = d >> 7;
            int pos = atomicAdd(&h[b], 1);
            packed[pos] = (unsigned)ei[e] | ((unsigned)(d & 127) << 17);
        }
    }
}

// per-bucket counting sort -> rp + col (writes land in one ~8KB window per block)
__global__ __launch_bounds__(256) void csr_k(const unsigned* __restrict__ packed,
                                             const int* __restrict__ bstart,
                                             int* __restrict__ rp, int* __restrict__ col) {
    __shared__ int hc[128], hb[128], sc[128];
    int t = threadIdx.x, b = blockIdx.x;
    int s0 = bstart[b], nb = bstart[b + 1] - s0;
    if (t < 128) hc[t] = 0;
    __syncthreads();
    for (int i = t; i < nb; i += 256) {
        unsigned u = packed[s0 + i];
        atomicAdd(&hc[u >> 17], 1);
    }
    __syncthreads();
    if (t < 128) sc[t] = hc[t];
    __syncthreads();
    for (int off = 1; off < 128; off <<= 1) {
        int u = 0;
        if (t < 128 && t >= off) u = sc[t - off];
        __syncthreads();
        if (t < 128) sc[t] += u;
        __syncthreads();
    }
    if (t < 128) {
        int ex = s0 + sc[t] - hc[t];
        int node = b * 128 + t;
        if (node < NN) rp[node] = ex;
        hb[t] = ex;
    }
    if (b == 0 && t == 0) rp[NN] = NE;
    __syncthreads();
    for (int i = t; i < nb; i += 256) {
        unsigned u = packed[s0 + i];
        int pos = atomicAdd(&hb[u >> 17], 1);
        col[pos] = (int)(u & 0x1FFFFu);
    }
}

// ---------------- aggregation: agg[i] = x[i] + sum_{j->i} x[j] ----------------
__global__ __launch_bounds__(256) void agg_k(const float* __restrict__ x, const int* __restrict__ rp,
                                             const int* __restrict__ col, float* __restrict__ agg) {
    int node = blockIdx.x * 8 + (threadIdx.x >> 5);
    int ch = threadIdx.x & 31;
    const float4* xv = (const float4*)x;
    float4 a = xv[node * 32 + ch];
    int beg = rp[node], end = rp[node + 1];
    for (int p = beg; p < end; ++p) {
        int s = col[p];
        float4 v = xv[s * 32 + ch];
        a.x += v.x; a.y += v.y; a.z += v.z; a.w += v.w;
    }
    ((float4*)agg)[node * 32 + ch] = a;
}

// ---------------- fp32 tiled GEMM, out = epi(A @ W + b) ----------------
template <int DOUT, int EPI>
__global__ __launch_bounds__(256, 2) void gemm_k(
    const float* __restrict__ A, const float* __restrict__ W, const float* __restrict__ bias,
    const float* __restrict__ bng, const float* __restrict__ bnb,
    const float* __restrict__ bnm, const float* __restrict__ bnv,
    const float* __restrict__ xres, float* __restrict__ out) {
    constexpr int TM = 64;
    constexpr int KT = 32;
    constexpr int NCG = DOUT / 4;
    constexpr int NRG = 256 / NCG;
    constexpr int RPT = TM / NRG;

    const int t = threadIdx.x;
    const int cg = t % NCG;
    const int rg = t / NCG;
    const int r0 = blockIdx.x * TM;

    __shared__ float Ws[KT * DOUT];
    __shared__ float xs[KT][TM + 4];

    float acc[RPT][4];
#pragma unroll
    for (int i = 0; i < RPT; ++i)
#pragma unroll
        for (int j = 0; j < 4; ++j) acc[i][j] = 0.f;

    for (int kt = 0; kt < DH; kt += KT) {
        __syncthreads();
        for (int i = t * 4; i < KT * DOUT; i += 1024)
            *(float4*)&Ws[i] = *(const float4*)&W[kt * DOUT + i];
        {
            int row = t >> 2;
            int kq = t & 3;
            bool ok = (r0 + row) < NN;
            const float* src = A + (size_t)(r0 + row) * DH + kt + kq * 8;
            float4 v0 = ok ? *(const float4*)src : make_float4(0.f, 0.f, 0.f, 0.f);
            float4 v1 = ok ? *(const float4*)(src + 4) : make_float4(0.f, 0.f, 0.f, 0.f);
            int kb = kq * 8;
            xs[kb + 0][row] = v0.x; xs[kb + 1][row] = v0.y;
            xs[kb + 2][row] = v0.z; xs[kb + 3][row] = v0.w;
            xs[kb + 4][row] = v1.x; xs[kb + 5][row] = v1.y;
            xs[kb + 6][row] = v1.z; xs[kb + 7][row] = v1.w;
        }
        __syncthreads();
#pragma unroll
        for (int k = 0; k < KT; ++k) {
            float4 wv = *(const float4*)&Ws[k * DOUT + cg * 4];
            const float4* xp = (const float4*)&xs[k][rg * RPT];
#pragma unroll
            for (int i4 = 0; i4 < RPT / 4; ++i4) {
                float4 xq = xp[i4];
                float xv[4] = {xq.x, xq.y, xq.z, xq.w};
#pragma unroll
                for (int ii = 0; ii < 4; ++ii) {
                    int i = i4 * 4 + ii;
                    acc[i][0] += xv[ii] * wv.x;
                    acc[i][1] += xv[ii] * wv.y;
                    acc[i][2] += xv[ii] * wv.z;
                    acc[i][3] += xv[ii] * wv.w;
                }
            }
        }
    }

    const int c0 = cg * 4;
    if constexpr (EPI == 0) {
        float4 bv = *(const float4*)&bias[c0];
#pragma unroll
        for (int i = 0; i < RPT; ++i) {
            int row = r0 + rg * RPT + i;
            if (row < NN) {
                float4 o;
                o.x = fmaxf(acc[i][0] + bv.x, 0.f);
                o.y = fmaxf(acc[i][1] + bv.y, 0.f);
                o.z = fmaxf(acc[i][2] + bv.z, 0.f);
                o.w = fmaxf(acc[i][3] + bv.w, 0.f);
                *(float4*)&out[(size_t)row * DOUT + c0] = o;
            }
        }
    } else if constexpr (EPI == 1) {
        float4 bv = *(const float4*)&bias[c0];
        float4 g4 = *(const float4*)&bng[c0];
        float4 b4 = *(const float4*)&bnb[c0];
        float4 m4 = *(const float4*)&bnm[c0];
        float4 v4 = *(const float4*)&bnv[c0];
        float sc[4], off[4];
        sc[0] = g4.x * rsqrtf(v4.x + BN_EPS); off[0] = (bv.x - m4.x) * sc[0] + b4.x;
        sc[1] = g4.y * rsqrtf(v4.y + BN_EPS); off[1] = (bv.y - m4.y) * sc[1] + b4.y;
        sc[2] = g4.z * rsqrtf(v4.z + BN_EPS); off[2] = (bv.z - m4.z) * sc[2] + b4.z;
        sc[3] = g4.w * rsqrtf(v4.w + BN_EPS); off[3] = (bv.w - m4.w) * sc[3] + b4.w;
#pragma unroll
        for (int i = 0; i < RPT; ++i) {
            int row = r0 + rg * RPT + i;
            if (row < NN) {
                float4 xr = *(const float4*)&xres[(size_t)row * DH + c0];
                float4 o;
                o.x = fmaxf(acc[i][0] * sc[0] + off[0], 0.f) + xr.x;
                o.y = fmaxf(acc[i][1] * sc[1] + off[1], 0.f) + xr.y;
                o.z = fmaxf(acc[i][2] * sc[2] + off[2], 0.f) + xr.z;
                o.w = fmaxf(acc[i][3] * sc[3] + off[3], 0.f) + xr.w;
                *(float4*)&out[(size_t)row * DH + c0] = o;
            }
        }
    } else {
        float4 bv = *(const float4*)&bias[c0];
#pragma unroll
        for (int i = 0; i < RPT; ++i) {
            float v0 = acc[i][0] + bv.x, v1 = acc[i][1] + bv.y;
            float v2 = acc[i][2] + bv.z, v3 = acc[i][3] + bv.w;
            float mx = fmaxf(fmaxf(v0, v1), fmaxf(v2, v3));
            for (int d = 1; d < 16; d <<= 1) mx = fmaxf(mx, __shfl_xor(mx, d));
            float sm = expf(v0 - mx) + expf(v1 - mx) + expf(v2 - mx) + expf(v3 - mx);
            for (int d = 1; d < 16; d <<= 1) sm += __shfl_xor(sm, d);
            float L = mx + logf(sm);
            int row = r0 + rg * RPT + i;
            if (row < NN) {
                float4 o = make_float4(v0 - L, v1 - L, v2 - L, v3 - L);
                *(float4*)&out[(size_t)row * DO2 + c0] = o;
            }
        }
    }
}

extern "C" void kernel_launch(void* const* d_in, const int* in_sizes, int n_in,
                              void* d_out, int out_size, void* d_ws, size_t ws_size,
                              hipStream_t stream) {
    const float* x = (const float*)d_in[0];
    const int* ei = (const int*)d_in[1];
    const float* W1_0 = (const float*)d_in[2];
    const float* b1_0 = (const float*)d_in[3];
    const float* W2_0 = (const float*)d_in[4];
    const float* b2_0 = (const float*)d_in[5];
    const float* W1_1 = (const float*)d_in[6];
    const float* b1_1 = (const float*)d_in[7];
    const float* W2_1 = (const float*)d_in[8];
    const float* b2_1 = (const float*)d_in[9];
    const float* W1_2 = (const float*)d_in[10];
    const float* b1_2 = (const float*)d_in[11];
    const float* W2_2 = (const float*)d_in[12];
    const float* b2_2 = (const float*)d_in[13];
    const float* g0 = (const float*)d_in[14];
    const float* be0 = (const float*)d_in[15];
    const float* m0 = (const float*)d_in[16];
    const float* v0 = (const float*)d_in[17];
    const float* g1 = (const float*)d_in[18];
    const float* be1 = (const float*)d_in[19];
    const float* m1 = (const float*)d_in[20];
    const float* v1 = (const float*)d_in[21];
    float* out = (float*)d_out;

    // ws layout (bytes):
    // x_cur 51,200,000 | aggh 51,200,000 (packed overlays first 6.4MB, transient)
    // rp 400,128 | col 6,400,000 | bstart 4096 | bcnt 4096 | bcur 4096
    char* ws = (char*)d_ws;
    float* x_cur = (float*)(ws);
    float* aggh = (float*)(ws + 51200000);
    unsigned* packed = (unsigned*)aggh;     // transient during CSR build only
    int* rp = (int*)(ws + 102400000);
    int* col = (int*)(ws + 102400000 + 400128);
    int* bstart = (int*)(ws + 102400000 + 400128 + 6400000);
    int* bcnt = (int*)(ws + 102400000 + 400128 + 6400000 + 4096);
    int* bcur = (int*)(ws + 102400000 + 400128 + 6400000 + 8192);

    // --- CSR build (bucketed; all scatter writes bucket-dense) ---
    hipMemsetAsync(bcnt, 0, NB * sizeof(int), stream);
    bhist_k<<<NEB, 256, 0, stream>>>(ei + NE, bcnt);
    bscan_k<<<1, 1024, 0, stream>>>(bcnt, bstart, bcur);
    bscat_k<<<NEB, 256, 0, stream>>>(ei, bcur, packed);
    csr_k<<<NB, 256, 0, stream>>>(packed, bstart, rp, col);

    const int GA = NN / 8;         // 12500
    const int GG = (NN + 63) / 64; // 1563

    // layer 0
    agg_k<<<GA, 256, 0, stream>>>(x, rp, col, aggh);
    gemm_k<128, 0><<<GG, 256, 0, stream>>>(aggh, W1_0, b1_0, nullptr, nullptr, nullptr, nullptr, nullptr, aggh);
    gemm_k<128, 1><<<GG, 256, 0, stream>>>(aggh, W2_0, b2_0, g0, be0, m0, v0, x, x_cur);
    // layer 1
    agg_k<<<GA, 256, 0, stream>>>(x_cur, rp, col, aggh);
    gemm_k<128, 0><<<GG, 256, 0, stream>>>(aggh, W1_1, b1_1, nullptr, nullptr, nullptr, nullptr, nullptr, aggh);
    gemm_k<128, 1><<<GG, 256, 0, stream>>>(aggh, W2_1, b2_1, g1, be1, m1, v1, x_cur, x_cur);
    // layer 2
    agg_k<<<GA, 256, 0, stream>>>(x_cur, rp, col, aggh);
    gemm_k<128, 0><<<GG, 256, 0, stream>>>(aggh, W1_2, b1_2, nullptr, nullptr, nullptr, nullptr, nullptr, aggh);
    gemm_k<64, 2><<<GG, 256, 0, stream>>>(aggh, W2_2, b2_2, nullptr, nullptr, nullptr, nullptr, nullptr, out);
}

// Round 3
// 405.957 us; speedup vs baseline: 2.1257x; 1.7833x over previous
//
#include <hip/hip_runtime.h>
#include <math.h>

#define NN 100000
#define NE 1600000
#define DH 128
#define BN_EPS 1e-5f
#define NB 782            // buckets of 128 nodes
#define EPB 4096
#define NEB ((NE + EPB - 1) / EPB)   // 391

typedef short bf16x8 __attribute__((ext_vector_type(8)));
typedef float f32x4 __attribute__((ext_vector_type(4)));
typedef unsigned short ushort;
typedef ushort us8 __attribute__((ext_vector_type(8)));
typedef ushort us4 __attribute__((ext_vector_type(4)));

__device__ __forceinline__ ushort f2bf(float f) {
    unsigned u = __float_as_uint(f);
    unsigned r = (u + 0x7FFFu + ((u >> 16) & 1u)) >> 16;
    return (ushort)r;
}
__device__ __forceinline__ float bf2f(ushort h) { return __uint_as_float(((unsigned)h) << 16); }

// ---------------- CSR build via dst-buckets ----------------
__global__ __launch_bounds__(256) void bhist_k(const int* __restrict__ dst, int* __restrict__ bcnt) {
    __shared__ int h[NB];
    for (int i = threadIdx.x; i < NB; i += 256) h[i] = 0;
    __syncthreads();
    int base = blockIdx.x * EPB;
    for (int i = threadIdx.x; i < EPB; i += 256) {
        int e = base + i;
        if (e < NE) atomicAdd(&h[dst[e] >> 7], 1);
    }
    __syncthreads();
    for (int i = threadIdx.x; i < NB; i += 256) {
        int c = h[i];
        if (c) atomicAdd(&bcnt[i], c);
    }
}

__global__ __launch_bounds__(1024) void bscan_k(const int* __restrict__ bcnt, int* __restrict__ bstart,
                                                int* __restrict__ bcur) {
    __shared__ int s[1024];
    int t = threadIdx.x;
    int v = (t < NB) ? bcnt[t] : 0;
    s[t] = v;
    __syncthreads();
    for (int off = 1; off < 1024; off <<= 1) {
        int u = (t >= off) ? s[t - off] : 0;
        __syncthreads();
        s[t] += u;
        __syncthreads();
    }
    int ex = s[t] - v;
    if (t <= NB) bstart[t] = ex;
    if (t < NB) bcur[t] = ex;
}

__global__ __launch_bounds__(256) void bscat_k(const int* __restrict__ ei, int* __restrict__ bcur,
                                               unsigned* __restrict__ packed) {
    __shared__ int h[NB];
    for (int i = threadIdx.x; i < NB; i += 256) h[i] = 0;
    __syncthreads();
    int base = blockIdx.x * EPB;
    for (int i = threadIdx.x; i < EPB; i += 256) {
        int e = base + i;
        if (e < NE) atomicAdd(&h[ei[NE + e] >> 7], 1);
    }
    __syncthreads();
    for (int i = threadIdx.x; i < NB; i += 256) {
        int c = h[i];
        if (c) h[i] = atomicAdd(&bcur[i], c);
    }
    __syncthreads();
    for (int i = threadIdx.x; i < EPB; i += 256) {
        int e = base + i;
        if (e < NE) {
            int d = ei[NE + e];
            int b = d >> 7;
            int pos = atomicAdd(&h[b], 1);
            packed[pos] = (unsigned)ei[e] | ((unsigned)(d & 127) << 17);
        }
    }
}

__global__ __launch_bounds__(256) void csr_k(const unsigned* __restrict__ packed,
                                             const int* __restrict__ bstart,
                                             int* __restrict__ rp, int* __restrict__ col) {
    __shared__ int hc[128], hb[128], sc[128];
    int t = threadIdx.x, b = blockIdx.x;
    int s0 = bstart[b], nb = bstart[b + 1] - s0;
    if (t < 128) hc[t] = 0;
    __syncthreads();
    for (int i = t; i < nb; i += 256) {
        unsigned u = packed[s0 + i];
        atomicAdd(&hc[u >> 17], 1);
    }
    __syncthreads();
    if (t < 128) sc[t] = hc[t];
    __syncthreads();
    for (int off = 1; off < 128; off <<= 1) {
        int u = 0;
        if (t < 128 && t >= off) u = sc[t - off];
        __syncthreads();
        if (t < 128) sc[t] += u;
        __syncthreads();
    }
    if (t < 128) {
        int ex = s0 + sc[t] - hc[t];
        int node = b * 128 + t;
        if (node < NN) rp[node] = ex;
        hb[t] = ex;
    }
    if (b == 0 && t == 0) rp[NN] = NE;
    __syncthreads();
    for (int i = t; i < nb; i += 256) {
        unsigned u = packed[s0 + i];
        int pos = atomicAdd(&hb[u >> 17], 1);
        col[pos] = (int)(u & 0x1FFFFu);
    }
}

// ---------------- converts ----------------
__global__ __launch_bounds__(256) void cvtx_k(const float* __restrict__ x, ushort* __restrict__ xb) {
    int i = blockIdx.x * 256 + threadIdx.x;  // one float4 per thread
    float4 v = ((const float4*)x)[i];
    us4 o;
    o[0] = f2bf(v.x); o[1] = f2bf(v.y); o[2] = f2bf(v.z); o[3] = f2bf(v.w);
    ((us4*)xb)[i] = o;
}

// pack W [128][DOUT] fp32 -> fragment-linear bf16: Wf[((kt*NT+nt)*64+l)*8+e] = W[kt*32+(l>>4)*8+e][nt*16+(l&15)]
template <int DOUT>
__global__ __launch_bounds__(256) void packw_k(const float* __restrict__ W, ushort* __restrict__ Wf) {
    constexpr int NT = DOUT / 16;
    int idx = blockIdx.x * 256 + threadIdx.x;
    if (idx >= 4 * NT * 64) return;
    int l = idx & 63;
    int nt = (idx >> 6) % NT;
    int kt = idx / (NT * 64);
    int colw = nt * 16 + (l & 15);
    int k0 = kt * 32 + (l >> 4) * 8;
    us8 o;
#pragma unroll
    for (int e = 0; e < 8; ++e) o[e] = f2bf(W[(k0 + e) * DOUT + colw]);
    ((us8*)Wf)[idx] = o;
}

// ---------------- aggregation (bf16): agg[i] = x[i] + sum_{j->i} x[j] ----------------
__global__ __launch_bounds__(256) void aggb_k(const ushort* __restrict__ x, const int* __restrict__ rp,
                                              const int* __restrict__ col, ushort* __restrict__ agg) {
    int node = blockIdx.x * 16 + (threadIdx.x >> 4);
    int ch = threadIdx.x & 15;  // 16 chunks of 8 bf16 per 128-dim row
    const us8* xv = (const us8*)x;
    us8 self = xv[node * 16 + ch];
    float a[8];
#pragma unroll
    for (int i = 0; i < 8; ++i) a[i] = bf2f(self[i]);
    int beg = rp[node], end = rp[node + 1];
    for (int p = beg; p < end; ++p) {
        int s = col[p];
        us8 v = xv[s * 16 + ch];
#pragma unroll
        for (int i = 0; i < 8; ++i) a[i] += bf2f(v[i]);
    }
    us8 o;
#pragma unroll
    for (int i = 0; i < 8; ++i) o[i] = f2bf(a[i]);
    ((us8*)agg)[node * 16 + ch] = o;
}

// ---------------- fused MLP: out = epi( relu(A@W1+b1) @ W2 + b2 ) ----------------
// 256 threads = 4 waves; 64 rows/block; wave w owns rows [w*16, w*16+16).
// FINAL=0: BN+relu+residual -> bf16 outb.  FINAL=1: log_softmax -> fp32 outf (DOUT=64).
template <int DOUT, int FINAL>
__global__ __launch_bounds__(256) void mlp_k(
    const ushort* __restrict__ A, const ushort* __restrict__ W1f, const ushort* __restrict__ W2f,
    const float* __restrict__ b1, const float* __restrict__ b2,
    const float* __restrict__ bng, const float* __restrict__ bnb,
    const float* __restrict__ bnm, const float* __restrict__ bnv,
    const ushort* __restrict__ xres, ushort* __restrict__ outb, float* __restrict__ outf) {
    constexpr int NT1 = 8;           // 128 hidden cols / 16
    constexpr int NT2 = DOUT / 16;
    __shared__ ushort hlds[64 * 128];  // 16KB, XOR-swizzled
    const int t = threadIdx.x;
    const int w = t >> 6, l = t & 63;
    const int lrow = l & 15, lkg = l >> 4;
    const int mrow0 = blockIdx.x * 64 + w * 16;

    // ---- stage 1: h = relu(A @ W1 + b1) ----
    f32x4 acc1[NT1];
#pragma unroll
    for (int nt = 0; nt < NT1; ++nt) acc1[nt] = f32x4{0.f, 0.f, 0.f, 0.f};
    for (int kt = 0; kt < 4; ++kt) {
        int grow = mrow0 + lrow;
        bf16x8 a = bf16x8{0, 0, 0, 0, 0, 0, 0, 0};
        if (grow < NN) a = *(const bf16x8*)(A + (size_t)grow * 128 + kt * 32 + lkg * 8);
        const bf16x8* wp = (const bf16x8*)W1f + (size_t)(kt * NT1) * 64 + l;
#pragma unroll
        for (int nt = 0; nt < NT1; ++nt) {
            bf16x8 b = wp[nt * 64];
            acc1[nt] = __builtin_amdgcn_mfma_f32_16x16x32_bf16(a, b, acc1[nt], 0, 0, 0);
        }
    }
#pragma unroll
    for (int nt = 0; nt < NT1; ++nt) {
        int colb = nt * 16 + lrow;
        float bias = b1[colb];
#pragma unroll
        for (int r = 0; r < 4; ++r) {
            int rr = lkg * 4 + r;
            float hv = fmaxf(acc1[nt][r] + bias, 0.f);
            int row = w * 16 + rr;
            int byte = (row * 256 + colb * 2) ^ ((rr & 7) << 4);
            *(ushort*)((char*)hlds + byte) = f2bf(hv);
        }
    }
    __syncthreads();

    // ---- stage 2: acc2 = h @ W2 ----
    f32x4 acc2[NT2];
#pragma unroll
    for (int nt = 0; nt < NT2; ++nt) acc2[nt] = f32x4{0.f, 0.f, 0.f, 0.f};
    for (int kt = 0; kt < 4; ++kt) {
        int row = w * 16 + lrow;
        int byte = (row * 256 + (kt * 32 + lkg * 8) * 2) ^ ((lrow & 7) << 4);
        bf16x8 a = *(const bf16x8*)((char*)hlds + byte);
        const bf16x8* wp = (const bf16x8*)W2f + (size_t)(kt * NT2) * 64 + l;
#pragma unroll
        for (int nt = 0; nt < NT2; ++nt) {
            bf16x8 b = wp[nt * 64];
            acc2[nt] = __builtin_amdgcn_mfma_f32_16x16x32_bf16(a, b, acc2[nt], 0, 0, 0);
        }
    }

    // ---- epilogue ----
    if constexpr (FINAL == 0) {
#pragma unroll
        for (int nt = 0; nt < NT2; ++nt) {
            int colb = nt * 16 + lrow;
            float sc = bng[colb] * rsqrtf(bnv[colb] + BN_EPS);
            float of = (b2[colb] - bnm[colb]) * sc + bnb[colb];
#pragma unroll
            for (int r = 0; r < 4; ++r) {
                int grow = mrow0 + lkg * 4 + r;
                if (grow < NN) {
                    float xr = bf2f(xres[(size_t)grow * 128 + colb]);
                    float o = fmaxf(acc2[nt][r] * sc + of, 0.f) + xr;
                    outb[(size_t)grow * 128 + colb] = f2bf(o);
                }
            }
        }
    } else {
        float bb[4];
#pragma unroll
        for (int nt = 0; nt < 4; ++nt) bb[nt] = b2[nt * 16 + lrow];
#pragma unroll
        for (int r = 0; r < 4; ++r) {
            float v0 = acc2[0][r] + bb[0], v1 = acc2[1][r] + bb[1];
            float v2 = acc2[2][r] + bb[2], v3 = acc2[3][r] + bb[3];
            float mx = fmaxf(fmaxf(v0, v1), fmaxf(v2, v3));
            for (int d = 1; d < 16; d <<= 1) mx = fmaxf(mx, __shfl_xor(mx, d));
            float sm = expf(v0 - mx) + expf(v1 - mx) + expf(v2 - mx) + expf(v3 - mx);
            for (int d = 1; d < 16; d <<= 1) sm += __shfl_xor(sm, d);
            float L = mx + logf(sm);
            int grow = mrow0 + lkg * 4 + r;
            if (grow < NN) {
                outf[(size_t)grow * 64 + 0 + lrow] = v0 - L;
                outf[(size_t)grow * 64 + 16 + lrow] = v1 - L;
                outf[(size_t)grow * 64 + 32 + lrow] = v2 - L;
                outf[(size_t)grow * 64 + 48 + lrow] = v3 - L;
            }
        }
    }
}

extern "C" void kernel_launch(void* const* d_in, const int* in_sizes, int n_in,
                              void* d_out, int out_size, void* d_ws, size_t ws_size,
                              hipStream_t stream) {
    const float* x = (const float*)d_in[0];
    const int* ei = (const int*)d_in[1];
    const float* W1_0 = (const float*)d_in[2];
    const float* b1_0 = (const float*)d_in[3];
    const float* W2_0 = (const float*)d_in[4];
    const float* b2_0 = (const float*)d_in[5];
    const float* W1_1 = (const float*)d_in[6];
    const float* b1_1 = (const float*)d_in[7];
    const float* W2_1 = (const float*)d_in[8];
    const float* b2_1 = (const float*)d_in[9];
    const float* W1_2 = (const float*)d_in[10];
    const float* b1_2 = (const float*)d_in[11];
    const float* W2_2 = (const float*)d_in[12];
    const float* b2_2 = (const float*)d_in[13];
    const float* g0 = (const float*)d_in[14];
    const float* be0 = (const float*)d_in[15];
    const float* m0 = (const float*)d_in[16];
    const float* v0 = (const float*)d_in[17];
    const float* g1 = (const float*)d_in[18];
    const float* be1 = (const float*)d_in[19];
    const float* m1 = (const float*)d_in[20];
    const float* v1 = (const float*)d_in[21];
    float* out = (float*)d_out;

    // ws layout (bytes):
    // xb0 25,600,000 | xb1 25,600,000 | aggh 25,600,000 (packed overlays) |
    // rp 400,128 | col 6,400,000 | bstart 4,096 | bcnt 4,096 | bcur 4,096 | Wf 5*32,768
    char* ws = (char*)d_ws;
    ushort* xb0 = (ushort*)(ws);
    ushort* xb1 = (ushort*)(ws + 25600000);
    ushort* aggh = (ushort*)(ws + 51200000);
    unsigned* packed = (unsigned*)aggh;
    int* rp = (int*)(ws + 76800000);
    int* col = (int*)(ws + 76800000 + 400128);
    int* bstart = (int*)(ws + 76800000 + 400128 + 6400000);
    int* bcnt = (int*)(ws + 76800000 + 400128 + 6400000 + 4096);
    int* bcur = (int*)(ws + 76800000 + 400128 + 6400000 + 8192);
    ushort* W10f = (ushort*)(ws + 76800000 + 400128 + 6400000 + 12288);
    ushort* W20f = W10f + 16384;
    ushort* W11f = W20f + 16384;
    ushort* W21f = W11f + 16384;
    ushort* W12f = W21f + 16384;
    ushort* W22f = W12f + 16384;   // DOUT=64: 8192 ushorts

    // --- CSR build ---
    hipMemsetAsync(bcnt, 0, NB * sizeof(int), stream);
    bhist_k<<<NEB, 256, 0, stream>>>(ei + NE, bcnt);
    bscan_k<<<1, 1024, 0, stream>>>(bcnt, bstart, bcur);
    bscat_k<<<NEB, 256, 0, stream>>>(ei, bcur, packed);
    csr_k<<<NB, 256, 0, stream>>>(packed, bstart, rp, col);

    // --- converts ---
    cvtx_k<<<12500, 256, 0, stream>>>(x, xb0);
    packw_k<128><<<8, 256, 0, stream>>>(W1_0, W10f);
    packw_k<128><<<8, 256, 0, stream>>>(W2_0, W20f);
    packw_k<128><<<8, 256, 0, stream>>>(W1_1, W11f);
    packw_k<128><<<8, 256, 0, stream>>>(W2_1, W21f);
    packw_k<128><<<8, 256, 0, stream>>>(W1_2, W12f);
    packw_k<64><<<4, 256, 0, stream>>>(W2_2, W22f);

    const int GA = NN / 16;        // 6250
    const int GG = (NN + 63) / 64; // 1563

    // layer 0
    aggb_k<<<GA, 256, 0, stream>>>(xb0, rp, col, aggh);
    mlp_k<128, 0><<<GG, 256, 0, stream>>>(aggh, W10f, W20f, b1_0, b2_0, g0, be0, m0, v0, xb0, xb1, nullptr);
    // layer 1
    aggb_k<<<GA, 256, 0, stream>>>(xb1, rp, col, aggh);
    mlp_k<128, 0><<<GG, 256, 0, stream>>>(aggh, W11f, W21f, b1_1, b2_1, g1, be1, m1, v1, xb1, xb0, nullptr);
    // layer 2
    aggb_k<<<GA, 256, 0, stream>>>(xb0, rp, col, aggh);
    mlp_k<64, 1><<<GG, 256, 0, stream>>>(aggh, W12f, W22f, b1_2, b2_2, nullptr, nullptr, nullptr, nullptr, nullptr, nullptr, out);
}